// Round 3
// baseline (165.994 us; speedup 1.0000x reference)
//
#include <hip/hip_runtime.h>
#include <math.h>

#define D 8
#define K 32
constexpr int BLOCK = 256;
constexpr int GRID  = 1024;

// numpy pairwise-sum tree for n=8: ((p0+p1)+(p2+p3))+((p4+p5)+(p6+p7)),
// all roundings explicit (no contraction, no reassociation).
__device__ __forceinline__ float pairwise8_sq(const float* v) {
    float p[D];
    #pragma unroll
    for (int d = 0; d < D; ++d) p[d] = __fmul_rn(v[d], v[d]);
    return __fadd_rn(
        __fadd_rn(__fadd_rn(p[0], p[1]), __fadd_rn(p[2], p[3])),
        __fadd_rn(__fadd_rn(p[4], p[5]), __fadd_rn(p[6], p[7])));
}

__global__ __launch_bounds__(BLOCK) void vq_main(
        const float* __restrict__ z,
        const float* __restrict__ cb,
        float* __restrict__ zq,
        double* __restrict__ sumsq,
        unsigned int* __restrict__ hist,
        int n)
{
    __shared__ float cb_s[K * D];
    __shared__ float c2_s[K];
    __shared__ unsigned int h_s[K];
    __shared__ float wsum[BLOCK / 64];

    const int tid = threadIdx.x;
    if (tid < K * D) cb_s[tid] = cb[tid];
    if (tid < K) h_s[tid] = 0u;
    __syncthreads();
    if (tid < K) {
        // c2 exactly as np.sum(cb*cb, axis=1): rounded squares + pairwise tree
        c2_s[tid] = pairwise8_sq(&cb_s[tid * D]);
    }
    __syncthreads();

    float lsum = 0.f;
    const int gtid   = blockIdx.x * BLOCK + tid;
    const int stride = BLOCK * GRID;

    for (int r = gtid; r < n; r += stride) {
        const float4* zp = (const float4*)(z + (size_t)r * D);
        float4 a = zp[0];
        float4 b = zp[1];
        float zr[D] = {a.x, a.y, a.z, a.w, b.x, b.y, b.z, b.w};

        // z2 exactly as np.sum(z*z, axis=1)
        float z2 = pairwise8_sq(zr);

        float best = 3.4e38f;
        int   bidx = 0;
        #pragma unroll
        for (int k = 0; k < K; ++k) {
            // dot exactly as OpenBLAS sgemm K=8: sequential FMA, acc from 0
            float dot = 0.f;
            #pragma unroll
            for (int d = 0; d < D; ++d)
                dot = __builtin_fmaf(zr[d], cb_s[k * D + d], dot);
            // (z2 - 2*dot) + c2, left-to-right, no contraction
            float dist = __fadd_rn(__fsub_rn(z2, __fmul_rn(2.0f, dot)), c2_s[k]);
            if (dist < best) { best = dist; bidx = k; }  // first-index tie-break
        }

        atomicAdd(&h_s[bidx], 1u);

        float o[D];
        #pragma unroll
        for (int d = 0; d < D; ++d) {
            float cq   = cb_s[bidx * D + d];
            float diff = __fsub_rn(cq, zr[d]);   // (z_q - z), one rounding
            lsum += diff * diff;
            o[d] = __fadd_rn(zr[d], diff);       // z + (z_q - z), one rounding
        }
        float4* op = (float4*)(zq + (size_t)r * D);
        op[0] = make_float4(o[0], o[1], o[2], o[3]);
        op[1] = make_float4(o[4], o[5], o[6], o[7]);
    }

    // wave(64)-level shuffle reduction of the squared-error sum
    #pragma unroll
    for (int off = 32; off > 0; off >>= 1)
        lsum += __shfl_down(lsum, off, 64);
    const int wave = tid >> 6;
    if ((tid & 63) == 0) wsum[wave] = lsum;
    __syncthreads();
    if (tid == 0) {
        float t = 0.f;
        #pragma unroll
        for (int w = 0; w < BLOCK / 64; ++w) t += wsum[w];
        atomicAdd(sumsq, (double)t);          // 1024 atomics total — negligible
    }
    if (tid < K) atomicAdd(&hist[tid], h_s[tid]);
}

__global__ void vq_final(const double* __restrict__ sumsq,
                         const unsigned int* __restrict__ hist,
                         float* __restrict__ out,
                         long long nd, int n)
{
    if (threadIdx.x == 0) {
        double vq = 1.25 * (*sumsq) / (double)nd;
        double ent = 0.0;
        for (int k = 0; k < K; ++k) {
            double p = (double)hist[k] / (double)n;
            ent -= p * log(p + 1e-10);
        }
        out[nd]     = (float)vq;
        out[nd + 1] = (float)exp(ent);
    }
}

extern "C" void kernel_launch(void* const* d_in, const int* in_sizes, int n_in,
                              void* d_out, int out_size, void* d_ws, size_t ws_size,
                              hipStream_t stream)
{
    const float* z  = (const float*)d_in[0];
    const float* cb = (const float*)d_in[1];
    float* out      = (float*)d_out;

    const int n = in_sizes[0] / D;           // 2,097,152
    const long long nd = (long long)n * D;

    // workspace layout: [0..8) double sumsq, [64..192) uint hist[32]
    double*       sumsq = (double*)d_ws;
    unsigned int* hist  = (unsigned int*)((char*)d_ws + 64);

    // ws is re-poisoned to 0xAA before every launch — zero what we use.
    hipMemsetAsync(d_ws, 0, 256, stream);

    vq_main<<<GRID, BLOCK, 0, stream>>>(z, cb, out, sumsq, hist, n);
    vq_final<<<1, 64, 0, stream>>>(sumsq, hist, out, nd, n);
}